// Round 15
// baseline (286.886 us; speedup 1.0000x reference)
//
#include <hip/hip_runtime.h>
#include <stdint.h>

#define CONF_T 0.01f
#define NMS_T  0.45f
#define M_TOP  200
#define TK_BS  256    // topk block size
#define TCAP   2048   // topk bracket buffer capacity (LDS); overflow -> exact fallback

typedef float float4u __attribute__((ext_vector_type(4), aligned(4)));

__device__ __forceinline__ uint32_t fkey(float f) {
    uint32_t u = __float_as_uint(f);
    return (u & 0x80000000u) ? ~u : (u | 0x80000000u);
}
__device__ __forceinline__ float fkey_inv(uint32_t k) {
    uint32_t u = (k & 0x80000000u) ? (k & 0x7FFFFFFFu) : ~k;
    return __uint_as_float(u);
}

// Parallel suffix-scan bin selection over nb bins (nb multiple of 256).
__device__ __forceinline__ void suffix_select(
        uint32_t* hist, uint32_t* wsum, int nb, uint32_t pref, int shift,
        uint32_t wantv, uint32_t* s_prefix, uint32_t* s_want) {
    int tid = threadIdx.x;
    int lane = tid & 63, w = tid >> 6;
    int bpt = nb >> 8;
    int base = tid * bpt;
    uint32_t loc = 0;
    for (int j = 0; j < bpt; j++) loc += hist[base + j];
    uint32_t sfx = loc;
    #pragma unroll
    for (int d = 1; d < 64; d <<= 1) {
        uint32_t y = __shfl_down(sfx, d);
        if (lane + d < 64) sfx += y;
    }
    if (lane == 0) wsum[w] = sfx;
    __syncthreads();
    uint32_t later = 0;
    for (int j = w + 1; j < TK_BS / 64; j++) later += wsum[j];
    uint32_t run = (sfx - loc) + later;
    for (int j = bpt - 1; j >= 0; j--) {
        uint32_t h = hist[base + j];
        uint32_t s2 = run + h;
        if (run < wantv && s2 >= wantv) {
            *s_prefix = pref | ((uint32_t)(base + j) << shift);
            *s_want   = wantv - run;
        }
        run = s2;
    }
    __syncthreads();
}

__device__ __forceinline__ float4 decode_box(float4 l, float4 d) {
    float cx = d.x + (l.x * 0.1f) * d.z;
    float cy = d.y + (l.y * 0.1f) * d.w;
    float w  = d.z * expf(l.z * 0.2f);
    float h  = d.w * expf(l.w * 0.2f);
    float x1 = cx - w * 0.5f, y1 = cy - h * 0.5f;
    float x2 = x1 + w, y2 = y1 + h;
    float4 o;
    o.x = fminf(fmaxf(x1, 0.f), 1.f);
    o.y = fminf(fmaxf(y1, 0.f), 1.f);
    o.z = fminf(fmaxf(x2, 0.f), 1.f);
    o.w = fminf(fmaxf(y2, 0.f), 1.f);
    return o;
}

// ---------------- Kernel B: softmax + transpose (register-resident) + pcnt init ------
__global__ __launch_bounds__(256, 4) void softmax_kernel(
        const float* __restrict__ conf, float* __restrict__ sc,
        int* __restrict__ pcnt, int B, int N, int C) {
    int r = blockIdx.x * blockDim.x + threadIdx.x;
    if (r < B) pcnt[r] = 0;                 // zero pcnt for the nms dispatch
    if (r >= B * N) return;
    const float* p = conf + (size_t)r * 81;
    float v[81];
    #pragma unroll
    for (int i = 0; i < 20; i++) {
        float4u f = *(const float4u*)(p + 4 * i);
        v[4 * i] = f.x; v[4 * i + 1] = f.y; v[4 * i + 2] = f.z; v[4 * i + 3] = f.w;
    }
    v[80] = p[80];
    float m = v[0];
    #pragma unroll
    for (int c = 1; c < 81; c++) m = fmaxf(m, v[c]);
    float s = 0.f;
    #pragma unroll
    for (int c = 0; c < 81; c++) { float e = expf(v[c] - m); v[c] = e; s += e; }
    int b = r / N, n = r % N;
    float* obase = sc + ((size_t)b * (C - 1)) * N + n;
    #pragma unroll
    for (int c = 1; c < 81; c++) obase[(size_t)(c - 1) * N] = v[c] / s;
}

// ---------------- Kernel C: top-200 (sample bracket, MLP sweep) + inline decode ------
__global__ __launch_bounds__(TK_BS) void topk_kernel(
        const float* __restrict__ sc, const float* __restrict__ loc,
        const float* __restrict__ dbox,
        float* __restrict__ tk_sc, float* __restrict__ cand,
        int B, int N, int Cm1) {
    const uint32_t KEYN1 = 0x407FFFFFu;        // fkey(-1.0f)
    const uint32_t BIN_N1 = KEYN1 >> 21;       // 0x203
    __shared__ __align__(16) uint32_t hist[2048];
    __shared__ __align__(16) uint32_t tk[TCAP];
    __shared__ int      tix[TCAP];
    __shared__ uint32_t wsum[TK_BS / 64];
    __shared__ uint32_t s_prefix, s_want;
    __shared__ uint32_t ngt, ntie, tcnt;
    __shared__ float    e_val[256];
    __shared__ int      e_idx[256];
    __shared__ int      tiebuf[256];

    int row = blockIdx.x;                      // b*Cm1 + c
    int b = row / Cm1;
    int tid = threadIdx.x;
    const float* v = sc + (size_t)row * N;
    const float4* v4 = (const float4*)v;
    int n4 = N >> 2;

    // ---- sample phase (2048 strided samples; keys staged in tk[0..2047]) ----
    bool sampled = (N >= 2048) && ((N & 7) == 0);
    uint32_t lo_key = 0xFFFFFFFFu, hi_key = 0xFFFFFFFFu;
    if (sampled) {
        int stride = N >> 3;
        for (int s = 0; s < 8; s++) {
            float f = v[s * stride + tid];
            tk[s * 256 + tid] = fkey(f > CONF_T ? f : -1.0f);
        }
        for (int i = tid; i < 2048; i += TK_BS) hist[i] = 0;
        __syncthreads();
        for (int i = tid; i < 2048; i += TK_BS) atomicAdd(&hist[tk[i] >> 21], 1u);
        __syncthreads();
        suffix_select(hist, wsum, 2048, 0u, 21, 3u, &s_prefix, &s_want);
        uint32_t h = s_prefix >> 21;
        suffix_select(hist, wsum, 2048, 0u, 21, 25u, &s_prefix, &s_want);
        uint32_t l = s_prefix >> 21;
        hi_key = ((h + 1) << 21) - 1u;
        lo_key = (l << 21) - 1u;
        sampled = (l > BIN_N1);
    }

    e_val[tid] = -1.0f; e_idx[tid] = tid;
    if (tid == 0) { ngt = 0; ntie = 0; tcnt = 0; }
    __syncthreads();

    bool ok = false;
    uint32_t G = 0, T = 0;
    if (sampled) {
        // ---- the one full sweep: 8-way unrolled batch loads for MLP ----
        for (int i0 = tid; i0 < n4; i0 += 8 * TK_BS) {
            float4 f[8];
            #pragma unroll
            for (int u = 0; u < 8; u++) {
                int i = i0 + u * TK_BS;
                if (i < n4) f[u] = v4[i];
            }
            #pragma unroll
            for (int u = 0; u < 8; u++) {
                int i = i0 + u * TK_BS;
                if (i < n4) {
                    float mv[4] = { f[u].x > CONF_T ? f[u].x : -1.0f,
                                    f[u].y > CONF_T ? f[u].y : -1.0f,
                                    f[u].z > CONF_T ? f[u].z : -1.0f,
                                    f[u].w > CONF_T ? f[u].w : -1.0f };
                    #pragma unroll
                    for (int j = 0; j < 4; j++) {
                        uint32_t k = fkey(mv[j]);
                        if (k > lo_key) {
                            int idx = 4 * i + j;
                            if (k > hi_key) {
                                uint32_t p = atomicAdd(&ngt, 1u);
                                if (p < 256) { e_val[p] = mv[j]; e_idx[p] = idx; }
                            } else {
                                uint32_t p = atomicAdd(&tcnt, 1u);
                                if (p < TCAP) { tk[p] = k; tix[p] = idx; }
                            }
                        }
                    }
                }
            }
        }
        for (int i = (n4 << 2) + tid; i < N; i += TK_BS) {
            float f = v[i];
            float mv = f > CONF_T ? f : -1.0f;
            uint32_t k = fkey(mv);
            if (k > lo_key) {
                if (k > hi_key) {
                    uint32_t p = atomicAdd(&ngt, 1u);
                    if (p < 256) { e_val[p] = mv; e_idx[p] = i; }
                } else {
                    uint32_t p = atomicAdd(&tcnt, 1u);
                    if (p < TCAP) { tk[p] = k; tix[p] = i; }
                }
            }
        }
        __syncthreads();
        G = ngt; T = tcnt;
        ok = (G <= (uint32_t)M_TOP) && (T <= (uint32_t)TCAP) &&
             (G + T >= (uint32_t)M_TOP);
    }

    uint32_t kth = KEYN1, rfin = 0;
    if (ok) {
        uint32_t want_t = (uint32_t)M_TOP - G;
        if (want_t > 0) {
            for (int i = tid; i < 2048; i += TK_BS) hist[i] = 0;
            __syncthreads();
            for (int i = tid; i < (int)T; i += TK_BS) atomicAdd(&hist[tk[i] >> 21], 1u);
            __syncthreads();
            suffix_select(hist, wsum, 2048, 0u, 21, want_t, &s_prefix, &s_want);
            uint32_t pre0 = s_prefix, w0 = s_want;
            uint32_t bb0 = pre0 >> 21;
            for (int i = tid; i < 2048; i += TK_BS) hist[i] = 0;
            __syncthreads();
            for (int i = tid; i < (int)T; i += TK_BS)
                if ((tk[i] >> 21) == bb0) atomicAdd(&hist[(tk[i] >> 10) & 2047u], 1u);
            __syncthreads();
            suffix_select(hist, wsum, 2048, pre0, 10, w0, &s_prefix, &s_want);
            uint32_t pre1 = s_prefix, w1 = s_want;
            for (int i = tid; i < 1024; i += TK_BS) hist[i] = 0;
            __syncthreads();
            for (int i = tid; i < (int)T; i += TK_BS)
                if ((tk[i] >> 10) == (pre1 >> 10)) atomicAdd(&hist[tk[i] & 1023u], 1u);
            __syncthreads();
            suffix_select(hist, wsum, 1024, pre1, 0, w1, &s_prefix, &s_want);
            kth = s_prefix; rfin = s_want;
            for (int i = tid; i < (int)T; i += TK_BS) {
                uint32_t k = tk[i];
                if (k > kth) {
                    uint32_t p = atomicAdd(&ngt, 1u);
                    if (p < 256) { e_val[p] = fkey_inv(k); e_idx[p] = tix[i]; }
                } else if (k == kth) {
                    uint32_t p = atomicAdd(&ntie, 1u);
                    if (p < 256) tiebuf[p] = tix[i];
                }
            }
            __syncthreads();
        }
    } else {
        // ---- fallback: exact 2-sweep histogram path ----
        e_val[tid] = -1.0f; e_idx[tid] = tid;
        if (tid == 0) { ngt = 0; ntie = 0; tcnt = 0; }
        for (int i = tid; i < 2048; i += TK_BS) hist[i] = 0;
        __syncthreads();
        for (int i = tid; i < n4; i += TK_BS) {
            float4 f = v4[i];
            atomicAdd(&hist[fkey(f.x > CONF_T ? f.x : -1.0f) >> 21], 1u);
            atomicAdd(&hist[fkey(f.y > CONF_T ? f.y : -1.0f) >> 21], 1u);
            atomicAdd(&hist[fkey(f.z > CONF_T ? f.z : -1.0f) >> 21], 1u);
            atomicAdd(&hist[fkey(f.w > CONF_T ? f.w : -1.0f) >> 21], 1u);
        }
        for (int i = (n4 << 2) + tid; i < N; i += TK_BS)
            atomicAdd(&hist[fkey(v[i] > CONF_T ? v[i] : -1.0f) >> 21], 1u);
        __syncthreads();
        suffix_select(hist, wsum, 2048, 0u, 21, M_TOP, &s_prefix, &s_want);
        uint32_t b0 = s_prefix >> 21;
        uint32_t want1 = s_want;
        bool collect_ties = (b0 != BIN_N1);
        for (int i = tid; i < N; i += TK_BS) {
            float f = v[i];
            float mv = f > CONF_T ? f : -1.0f;
            uint32_t k = fkey(mv);
            uint32_t bin = k >> 21;
            if (bin > b0) {
                uint32_t p = atomicAdd(&ngt, 1u);
                if (p < 256) { e_val[p] = mv; e_idx[p] = i; }
            } else if (bin == b0 && collect_ties) {
                uint32_t p = atomicAdd(&tcnt, 1u);
                if (p < TCAP) { tk[p] = k; tix[p] = i; }
            }
        }
        __syncthreads();
        if (collect_ties && tcnt <= TCAP) {
            int Tl = (int)tcnt;
            for (int i = tid; i < 2048; i += TK_BS) hist[i] = 0;
            __syncthreads();
            for (int i = tid; i < Tl; i += TK_BS) atomicAdd(&hist[(tk[i] >> 10) & 2047u], 1u);
            __syncthreads();
            suffix_select(hist, wsum, 2048, b0 << 21, 10, want1, &s_prefix, &s_want);
            uint32_t pre2 = s_prefix; uint32_t want2 = s_want;
            uint32_t b1 = (pre2 >> 10) & 2047u;
            for (int i = tid; i < 1024; i += TK_BS) hist[i] = 0;
            __syncthreads();
            for (int i = tid; i < Tl; i += TK_BS)
                if (((tk[i] >> 10) & 2047u) == b1) atomicAdd(&hist[tk[i] & 1023u], 1u);
            __syncthreads();
            suffix_select(hist, wsum, 1024, pre2, 0, want2, &s_prefix, &s_want);
            kth = s_prefix; rfin = s_want;
            for (int i = tid; i < Tl; i += TK_BS) {
                uint32_t k = tk[i];
                if (k > kth) {
                    uint32_t p = atomicAdd(&ngt, 1u);
                    if (p < 256) { e_val[p] = fkey_inv(k); e_idx[p] = tix[i]; }
                } else if (k == kth) {
                    uint32_t p = atomicAdd(&ntie, 1u);
                    if (p < 256) tiebuf[p] = tix[i];
                }
            }
            __syncthreads();
        } else if (collect_ties) {
            const int shifts[2] = {10, 0};
            const int nbins_[2] = {2048, 1024};
            if (tid == 0) { s_prefix = b0 << 21; s_want = want1; }
            __syncthreads();
            for (int lev = 0; lev < 2; lev++) {
                int shift = shifts[lev];
                int nb = nbins_[lev];
                uint32_t bmask = (uint32_t)nb - 1u;
                uint32_t pref = s_prefix, wantv = s_want;
                uint32_t pmask = 0xFFFFFFFFu << (shift + ((nb == 2048) ? 11 : 10));
                for (int i = tid; i < nb; i += TK_BS) hist[i] = 0;
                __syncthreads();
                for (int i = tid; i < N; i += TK_BS) {
                    float f = v[i];
                    uint32_t k = fkey(f > CONF_T ? f : -1.0f);
                    if ((k & pmask) == (pref & pmask)) atomicAdd(&hist[(k >> shift) & bmask], 1u);
                }
                __syncthreads();
                suffix_select(hist, wsum, nb, pref, shift, wantv, &s_prefix, &s_want);
            }
            kth = s_prefix; rfin = s_want;
            for (int i = tid; i < N; i += TK_BS) {
                float f = v[i];
                float mv = f > CONF_T ? f : -1.0f;
                uint32_t k = fkey(mv);
                if ((k >> 21) == b0) {
                    if (k > kth) {
                        uint32_t p = atomicAdd(&ngt, 1u);
                        if (p < 256) { e_val[p] = mv; e_idx[p] = i; }
                    } else if (k == kth) {
                        uint32_t p = atomicAdd(&ntie, 1u);
                        if (p < 256) tiebuf[p] = i;
                    }
                }
            }
            __syncthreads();
        }
    }

    // ---- ties, rank order, inline box decode -> global tk_sc + cand ----
    uint32_t gcount = min(ngt, (uint32_t)M_TOP);
    uint32_t nt = min(ntie, 256u);
    if (tid < (int)nt) {
        int mine = tiebuf[tid];
        uint32_t rk = 0;
        for (uint32_t j = 0; j < nt; j++) if (tiebuf[j] < mine) rk++;
        if (rk < rfin) {
            uint32_t slot = gcount + rk;
            if (slot < M_TOP) { e_val[slot] = fkey_inv(kth); e_idx[slot] = mine; }
        }
    }
    __syncthreads();
    if (tid < M_TOP) {
        float mv = e_val[tid]; int mi = e_idx[tid];
        uint32_t mk = fkey(mv);
        uint32_t rk = 0;
        for (int j = 0; j < M_TOP; j++) {
            uint32_t jk = fkey(e_val[j]); int ji = e_idx[j];
            if (jk > mk || (jk == mk && ji < mi)) rk++;
        }
        size_t base = (size_t)row * M_TOP + rk;
        tk_sc[base] = mv;
        float4 l = ((const float4*)loc)[(size_t)b * N + mi];
        float4 d = ((const float4*)dbox)[mi];
        ((float4*)cand)[base] = decode_box(l, d);
    }
}

// ---------------- Kernel D: greedy NMS + compaction, one wave per row (standalone) ---
__global__ __launch_bounds__(64) void nms_kernel(
        const float* __restrict__ tk_sc, const float* __restrict__ cand,
        float* __restrict__ cmpval, int* __restrict__ cmpidx,
        int* __restrict__ pcnt, int M, int Cm1) {
    int row = blockIdx.x;
    int b = row / Cm1, c = row % Cm1;
    int lane = threadIdx.x;
    float x1[4], y1[4], x2[4], y2[4], ar[4], sv[4];
    int act[4], kf[4];
    #pragma unroll
    for (int s = 0; s < 4; s++) {
        int j = s * 64 + lane;
        if (j < M_TOP) {
            size_t base = (size_t)row * M_TOP + j;
            float4 bb = ((const float4*)cand)[base];
            x1[s] = bb.x; y1[s] = bb.y; x2[s] = bb.z; y2[s] = bb.w;
            ar[s] = (bb.z - bb.x) * (bb.w - bb.y);
            sv[s] = tk_sc[base];
        } else { x1[s] = 0.f; y1[s] = 0.f; x2[s] = 0.f; y2[s] = 0.f; ar[s] = 0.f; sv[s] = -1.0f; }
        act[s] = (sv[s] > CONF_T) ? 1 : 0;
        kf[s] = 0;
    }
    #pragma unroll
    for (int si = 0; si < 4; si++) {
        int lim = M_TOP - si * 64; if (lim > 64) lim = 64;
        for (int li = 0; li < lim; li++) {
            int a = __shfl(act[si], li);
            if (a) {
                if (lane == li) kf[si] = 1;
                float bx1 = __shfl(x1[si], li);
                float by1 = __shfl(y1[si], li);
                float bx2 = __shfl(x2[si], li);
                float by2 = __shfl(y2[si], li);
                float bar = __shfl(ar[si], li);
                #pragma unroll
                for (int s = 0; s < 4; s++) {
                    float xx1 = fmaxf(bx1, x1[s]);
                    float yy1 = fmaxf(by1, y1[s]);
                    float xx2 = fminf(bx2, x2[s]);
                    float yy2 = fminf(by2, y2[s]);
                    float inter = fmaxf(xx2 - xx1, 0.f) * fmaxf(yy2 - yy1, 0.f);
                    float uni = (ar[s] - inter) + bar;
                    float iou = inter / uni;
                    if (!(iou <= NMS_T)) act[s] = 0;   // NaN suppresses
                }
            }
        }
    }
    unsigned long long ball[4];
    int total = 0;
    #pragma unroll
    for (int s = 0; s < 4; s++) { ball[s] = __ballot(kf[s] != 0); total += (int)__popcll(ball[s]); }
    int base = 0;
    if (lane == 0 && total > 0) base = atomicAdd(&pcnt[b], total);
    base = __shfl(base, 0);
    unsigned long long lower = (lane == 0) ? 0ull : (~0ull >> (64 - lane));
    int off = base;
    #pragma unroll
    for (int s = 0; s < 4; s++) {
        if (kf[s]) {
            int pos = off + (int)__popcll(ball[s] & lower);
            cmpval[(size_t)b * M + pos] = sv[s];
            cmpidx[(size_t)b * M + pos] = c * M_TOP + s * 64 + lane;
        }
        off += (int)__popcll(ball[s]);
    }
}

// ---------------- Kernel E: top-200 of positives -> compact (val,idx) list ----------
#define GT_BS 1024
__global__ __launch_bounds__(GT_BS) void gtop_kernel(
        const float* __restrict__ cmpval, const int* __restrict__ cmpidx,
        const int* __restrict__ pcnt, float* __restrict__ gl_val,
        int* __restrict__ gl_idx, int* __restrict__ gl_cnt, int M) {
    int b = blockIdx.x;
    int tid = threadIdx.x;
    int P = pcnt[b];
    const float* cv = cmpval + (size_t)b * M;
    const int*   ci = cmpidx + (size_t)b * M;
    if (P <= M_TOP) {
        for (int i = tid; i < P; i += GT_BS) {
            gl_val[b * M_TOP + i] = cv[i];
            gl_idx[b * M_TOP + i] = ci[i];
        }
        if (tid == 0) gl_cnt[b] = P;
        return;
    }
    __shared__ uint32_t hist[256];
    __shared__ uint32_t s_prefix, s_want;
    __shared__ int tiebuf[256];
    __shared__ uint32_t ntie, wcnt;
    __shared__ int cutoff;
    if (tid == 0) { s_prefix = 0; s_want = M_TOP; }
    for (int pass = 0; pass < 4; pass++) {
        if (tid < 256) hist[tid] = 0;
        __syncthreads();
        uint32_t prefix = s_prefix;
        int shift = 24 - 8 * pass;
        for (int i = tid; i < P; i += GT_BS) {
            uint32_t k = fkey(cv[i]);
            bool ok = (pass == 0) || ((k >> (shift + 8)) == (prefix >> (shift + 8)));
            if (ok) atomicAdd(&hist[(k >> shift) & 255u], 1u);
        }
        __syncthreads();
        if (tid == 0) {
            uint32_t want = s_want, cum = 0; int bin = 0;
            for (int bb = 255; bb >= 0; bb--) {
                if (cum + hist[bb] >= want) { bin = bb; break; }
                cum += hist[bb];
            }
            s_want = want - cum;
            s_prefix = prefix | ((uint32_t)bin << shift);
        }
        __syncthreads();
    }
    uint32_t kth = s_prefix, rfin = s_want;
    if (tid == 0) { ntie = 0; cutoff = -1; wcnt = 0; }
    __syncthreads();
    for (int i = tid; i < P; i += GT_BS) {
        if (fkey(cv[i]) == kth) { uint32_t p = atomicAdd(&ntie, 1u); if (p < 256) tiebuf[p] = ci[i]; }
    }
    __syncthreads();
    uint32_t nt = min(ntie, 256u);
    if (tid < (int)nt) {
        int mine = tiebuf[tid];
        uint32_t rk = 0;
        for (uint32_t j = 0; j < nt; j++) if (tiebuf[j] < mine) rk++;
        if (rk == rfin - 1) cutoff = mine;
    }
    __syncthreads();
    int cut = cutoff;
    for (int i = tid; i < P; i += GT_BS) {
        uint32_t k = fkey(cv[i]);
        if (k > kth || (k == kth && ci[i] <= cut)) {
            uint32_t p = atomicAdd(&wcnt, 1u);
            gl_val[b * M_TOP + p] = cv[i];
            gl_idx[b * M_TOP + p] = ci[i];
        }
    }
    if (tid == 0) gl_cnt[b] = M_TOP;
}

// ---------------- Kernel F: per-class sort + FULL output write (no memset) ----------
__global__ __launch_bounds__(256) void out_kernel(
        const float* __restrict__ gl_val, const int* __restrict__ gl_idx,
        const int* __restrict__ gl_cnt, const float* __restrict__ cand,
        float* __restrict__ out, int C, int Cm1) {
    int row = blockIdx.x;   // b*C + cc
    int b = row / C, cc = row % C;
    int tid = threadIdx.x;
    size_t oslab = (size_t)row * M_TOP * 5;
    if (cc == 0) {
        for (int i = tid; i < M_TOP * 5; i += 256) out[oslab + i] = 0.0f;
        return;
    }
    int c = cc - 1;
    __shared__ float lv[M_TOP];
    __shared__ int   lm[M_TOP];
    __shared__ uint32_t nloc;
    if (tid == 0) nloc = 0;
    __syncthreads();
    int cnt = gl_cnt[b];
    for (int i = tid; i < cnt; i += 256) {
        int idx = gl_idx[b * M_TOP + i];
        if (idx / M_TOP == c) {
            uint32_t p = atomicAdd(&nloc, 1u);
            lv[p] = gl_val[b * M_TOP + i];
            lm[p] = idx % M_TOP;
        }
    }
    __syncthreads();
    int nc = (int)nloc;
    if (tid < M_TOP) {
        if (tid < nc) {
            float v = lv[tid]; int m = lm[tid];
            int rk = 0;
            for (int j = 0; j < nc; j++)
                if (lv[j] > v || (lv[j] == v && lm[j] < m)) rk++;
            float4 bb = ((const float4*)cand)[((size_t)(b * Cm1 + c)) * M_TOP + m];
            size_t o = oslab + (size_t)rk * 5;
            out[o] = v; out[o + 1] = bb.x; out[o + 2] = bb.y;
            out[o + 3] = bb.z; out[o + 4] = bb.w;
        } else {
            size_t o = oslab + (size_t)tid * 5;
            out[o] = 0.f; out[o + 1] = 0.f; out[o + 2] = 0.f;
            out[o + 3] = 0.f; out[o + 4] = 0.f;
        }
    }
}

extern "C" void kernel_launch(void* const* d_in, const int* in_sizes, int n_in,
                              void* d_out, int out_size, void* d_ws, size_t ws_size,
                              hipStream_t stream) {
    const float* loc  = (const float*)d_in[0];
    const float* conf = (const float*)d_in[1];
    const float* dbox = (const float*)d_in[2];
    int N   = in_sizes[2] / 4;
    int B   = in_sizes[0] / (4 * N);
    int C   = in_sizes[1] / (B * N);
    int Cm1 = C - 1;
    int M   = Cm1 * M_TOP;                 // 16000 per batch

    char* ws = (char*)d_ws;
    size_t off = 0;
    auto alloc = [&](size_t bytes) -> char* {
        char* p = ws + off;
        off = (off + bytes + 255) & ~(size_t)255;
        return p;
    };
    float* sc     = (float*)alloc((size_t)B * Cm1 * N * sizeof(float));
    float* tk_sc  = (float*)alloc((size_t)B * M * sizeof(float));
    float* cand   = (float*)alloc((size_t)B * M * 4 * sizeof(float));
    int*   pcnt   = (int*)alloc((size_t)B * sizeof(int));
    float* cmpval = (float*)alloc((size_t)B * M * sizeof(float));
    int*   cmpidx = (int*)alloc((size_t)B * M * sizeof(int));
    float* gl_val = (float*)alloc((size_t)B * M_TOP * sizeof(float));
    int*   gl_idx = (int*)alloc((size_t)B * M_TOP * sizeof(int));
    int*   gl_cnt = (int*)alloc((size_t)B * sizeof(int));

    int bn = B * N;
    softmax_kernel<<<(bn + 255) / 256, 256, 0, stream>>>(conf, sc, pcnt, B, N, C);
    topk_kernel<<<B * Cm1, TK_BS, 0, stream>>>(sc, loc, dbox, tk_sc, cand, B, N, Cm1);
    nms_kernel<<<B * Cm1, 64, 0, stream>>>(tk_sc, cand, cmpval, cmpidx, pcnt, M, Cm1);
    gtop_kernel<<<B, GT_BS, 0, stream>>>(cmpval, cmpidx, pcnt, gl_val, gl_idx, gl_cnt, M);
    out_kernel<<<B * C, 256, 0, stream>>>(gl_val, gl_idx, gl_cnt, cand, (float*)d_out, C, Cm1);
}

// Round 16
// 278.500 us; speedup vs baseline: 1.0301x; 1.0301x over previous
//
#include <hip/hip_runtime.h>
#include <stdint.h>

#define CONF_T 0.01f
#define NMS_T  0.45f
#define M_TOP  200
#define TK_BS  256    // topk block size
#define TCAP   2048   // topk bracket buffer capacity (LDS); overflow -> exact fallback

typedef float float4u __attribute__((ext_vector_type(4), aligned(4)));

__device__ __forceinline__ uint32_t fkey(float f) {
    uint32_t u = __float_as_uint(f);
    return (u & 0x80000000u) ? ~u : (u | 0x80000000u);
}
__device__ __forceinline__ float fkey_inv(uint32_t k) {
    uint32_t u = (k & 0x80000000u) ? (k & 0x7FFFFFFFu) : ~k;
    return __uint_as_float(u);
}

// Parallel suffix-scan bin selection over nb bins (nb multiple of 256).
__device__ __forceinline__ void suffix_select(
        uint32_t* hist, uint32_t* wsum, int nb, uint32_t pref, int shift,
        uint32_t wantv, uint32_t* s_prefix, uint32_t* s_want) {
    int tid = threadIdx.x;
    int lane = tid & 63, w = tid >> 6;
    int bpt = nb >> 8;
    int base = tid * bpt;
    uint32_t loc = 0;
    for (int j = 0; j < bpt; j++) loc += hist[base + j];
    uint32_t sfx = loc;
    #pragma unroll
    for (int d = 1; d < 64; d <<= 1) {
        uint32_t y = __shfl_down(sfx, d);
        if (lane + d < 64) sfx += y;
    }
    if (lane == 0) wsum[w] = sfx;
    __syncthreads();
    uint32_t later = 0;
    for (int j = w + 1; j < TK_BS / 64; j++) later += wsum[j];
    uint32_t run = (sfx - loc) + later;
    for (int j = bpt - 1; j >= 0; j--) {
        uint32_t h = hist[base + j];
        uint32_t s2 = run + h;
        if (run < wantv && s2 >= wantv) {
            *s_prefix = pref | ((uint32_t)(base + j) << shift);
            *s_want   = wantv - run;
        }
        run = s2;
    }
    __syncthreads();
}

// Dual-rank variant: finds boundary bins for TWO wants in one scan.
__device__ __forceinline__ void suffix_select2(
        uint32_t* hist, uint32_t* wsum, int nb, uint32_t want_a, uint32_t want_b,
        uint32_t* s_bin_a, uint32_t* s_bin_b) {
    int tid = threadIdx.x;
    int lane = tid & 63, w = tid >> 6;
    int bpt = nb >> 8;
    int base = tid * bpt;
    uint32_t loc = 0;
    for (int j = 0; j < bpt; j++) loc += hist[base + j];
    uint32_t sfx = loc;
    #pragma unroll
    for (int d = 1; d < 64; d <<= 1) {
        uint32_t y = __shfl_down(sfx, d);
        if (lane + d < 64) sfx += y;
    }
    if (lane == 0) wsum[w] = sfx;
    __syncthreads();
    uint32_t later = 0;
    for (int j = w + 1; j < TK_BS / 64; j++) later += wsum[j];
    uint32_t run = (sfx - loc) + later;
    for (int j = bpt - 1; j >= 0; j--) {
        uint32_t h = hist[base + j];
        uint32_t s2 = run + h;
        if (run < want_a && s2 >= want_a) *s_bin_a = (uint32_t)(base + j);
        if (run < want_b && s2 >= want_b) *s_bin_b = (uint32_t)(base + j);
        run = s2;
    }
    __syncthreads();
}

__device__ __forceinline__ float4 decode_box(float4 l, float4 d) {
    float cx = d.x + (l.x * 0.1f) * d.z;
    float cy = d.y + (l.y * 0.1f) * d.w;
    float w  = d.z * expf(l.z * 0.2f);
    float h  = d.w * expf(l.w * 0.2f);
    float x1 = cx - w * 0.5f, y1 = cy - h * 0.5f;
    float x2 = x1 + w, y2 = y1 + h;
    float4 o;
    o.x = fminf(fmaxf(x1, 0.f), 1.f);
    o.y = fminf(fmaxf(y1, 0.f), 1.f);
    o.z = fminf(fmaxf(x2, 0.f), 1.f);
    o.w = fminf(fmaxf(y2, 0.f), 1.f);
    return o;
}

// ---------------- Kernel B: softmax + transpose (register-resident) + pcnt init ------
__global__ __launch_bounds__(256, 4) void softmax_kernel(
        const float* __restrict__ conf, float* __restrict__ sc,
        int* __restrict__ pcnt, int B, int N, int C) {
    int r = blockIdx.x * blockDim.x + threadIdx.x;
    if (r < B) pcnt[r] = 0;                 // zero pcnt for the topk dispatch
    if (r >= B * N) return;
    const float* p = conf + (size_t)r * 81;
    float v[81];
    #pragma unroll
    for (int i = 0; i < 20; i++) {
        float4u f = *(const float4u*)(p + 4 * i);
        v[4 * i] = f.x; v[4 * i + 1] = f.y; v[4 * i + 2] = f.z; v[4 * i + 3] = f.w;
    }
    v[80] = p[80];
    float m = v[0];
    #pragma unroll
    for (int c = 1; c < 81; c++) m = fmaxf(m, v[c]);
    float s = 0.f;
    #pragma unroll
    for (int c = 0; c < 81; c++) { float e = expf(v[c] - m); v[c] = e; s += e; }
    int b = r / N, n = r % N;
    float* obase = sc + ((size_t)b * (C - 1)) * N + n;
    #pragma unroll
    for (int c = 1; c < 81; c++) obase[(size_t)(c - 1) * N] = v[c] / s;
}

// ---------------- Kernel C: top-200 + inline decode + fused serial-wave NMS ----------
__global__ __launch_bounds__(TK_BS) void topk_kernel(
        const float* __restrict__ sc, const float* __restrict__ loc,
        const float* __restrict__ dbox,
        float* __restrict__ cand,
        float* __restrict__ cmpval, int* __restrict__ cmpidx,
        int* __restrict__ pcnt,
        int B, int N, int Cm1, int M) {
    const uint32_t KEYN1 = 0x407FFFFFu;        // fkey(-1.0f)
    const uint32_t BIN_N1 = KEYN1 >> 21;       // 0x203
    __shared__ __align__(16) uint32_t hist[2048];
    __shared__ __align__(16) uint32_t tk[TCAP];
    __shared__ int      tix[TCAP];
    __shared__ uint32_t wsum[TK_BS / 64];
    __shared__ uint32_t s_prefix, s_want, s_bin_a, s_bin_b;
    __shared__ uint32_t ngt, ntie, tcnt;
    __shared__ float    e_val[256];
    __shared__ int      e_idx[256];
    __shared__ int      tiebuf[256];
    __shared__ float    s_sc[M_TOP];
    __shared__ float    s_x1[M_TOP], s_y1[M_TOP], s_x2[M_TOP], s_y2[M_TOP];

    int row = blockIdx.x;                      // b*Cm1 + c
    int b = row / Cm1, c = row % Cm1;
    int tid = threadIdx.x;
    const float* v = sc + (size_t)row * N;
    const float4* v4 = (const float4*)v;
    int n4 = N >> 2;

    // ---- sample phase: one histogram + ONE dual-rank scan ----
    bool sampled = (N >= 2048) && ((N & 7) == 0);
    uint32_t lo_key = 0xFFFFFFFFu, hi_key = 0xFFFFFFFFu;
    if (sampled) {
        int stride = N >> 3;
        for (int s = 0; s < 8; s++) {
            float f = v[s * stride + tid];
            tk[s * 256 + tid] = fkey(f > CONF_T ? f : -1.0f);
        }
        for (int i = tid; i < 2048; i += TK_BS) hist[i] = 0;
        __syncthreads();
        for (int i = tid; i < 2048; i += TK_BS) atomicAdd(&hist[tk[i] >> 21], 1u);
        __syncthreads();
        suffix_select2(hist, wsum, 2048, 3u, 25u, &s_bin_a, &s_bin_b);
        uint32_t h = s_bin_a, l = s_bin_b;
        hi_key = ((h + 1) << 21) - 1u;         // h=2047 wraps to 0xFFFFFFFF (G=0)
        lo_key = (l << 21) - 1u;
        sampled = (l > BIN_N1);
    }

    e_val[tid] = -1.0f; e_idx[tid] = tid;
    if (tid == 0) { ngt = 0; ntie = 0; tcnt = 0; }
    __syncthreads();

    bool ok = false;
    uint32_t G = 0, T = 0;
    if (sampled) {
        // ---- the one full sweep: 8-way unrolled batch loads for MLP ----
        for (int i0 = tid; i0 < n4; i0 += 8 * TK_BS) {
            float4 f[8];
            #pragma unroll
            for (int u = 0; u < 8; u++) {
                int i = i0 + u * TK_BS;
                if (i < n4) f[u] = v4[i];
            }
            #pragma unroll
            for (int u = 0; u < 8; u++) {
                int i = i0 + u * TK_BS;
                if (i < n4) {
                    float mv[4] = { f[u].x > CONF_T ? f[u].x : -1.0f,
                                    f[u].y > CONF_T ? f[u].y : -1.0f,
                                    f[u].z > CONF_T ? f[u].z : -1.0f,
                                    f[u].w > CONF_T ? f[u].w : -1.0f };
                    #pragma unroll
                    for (int j = 0; j < 4; j++) {
                        uint32_t k = fkey(mv[j]);
                        if (k > lo_key) {
                            int idx = 4 * i + j;
                            if (k > hi_key) {
                                uint32_t p = atomicAdd(&ngt, 1u);
                                if (p < 256) { e_val[p] = mv[j]; e_idx[p] = idx; }
                            } else {
                                uint32_t p = atomicAdd(&tcnt, 1u);
                                if (p < TCAP) { tk[p] = k; tix[p] = idx; }
                            }
                        }
                    }
                }
            }
        }
        for (int i = (n4 << 2) + tid; i < N; i += TK_BS) {
            float f = v[i];
            float mv = f > CONF_T ? f : -1.0f;
            uint32_t k = fkey(mv);
            if (k > lo_key) {
                if (k > hi_key) {
                    uint32_t p = atomicAdd(&ngt, 1u);
                    if (p < 256) { e_val[p] = mv; e_idx[p] = i; }
                } else {
                    uint32_t p = atomicAdd(&tcnt, 1u);
                    if (p < TCAP) { tk[p] = k; tix[p] = i; }
                }
            }
        }
        __syncthreads();
        G = ngt; T = tcnt;
        ok = (G <= (uint32_t)M_TOP) && (T <= (uint32_t)TCAP) &&
             (G + T >= (uint32_t)M_TOP);
    }

    uint32_t kth = KEYN1, rfin = 0;
    if (ok) {
        uint32_t want_t = (uint32_t)M_TOP - G;
        if (want_t > 0) {
            for (int i = tid; i < 2048; i += TK_BS) hist[i] = 0;
            __syncthreads();
            for (int i = tid; i < (int)T; i += TK_BS) atomicAdd(&hist[tk[i] >> 21], 1u);
            __syncthreads();
            suffix_select(hist, wsum, 2048, 0u, 21, want_t, &s_prefix, &s_want);
            uint32_t pre0 = s_prefix, w0 = s_want;
            uint32_t bb0 = pre0 >> 21;
            for (int i = tid; i < 2048; i += TK_BS) hist[i] = 0;
            __syncthreads();
            for (int i = tid; i < (int)T; i += TK_BS)
                if ((tk[i] >> 21) == bb0) atomicAdd(&hist[(tk[i] >> 10) & 2047u], 1u);
            __syncthreads();
            suffix_select(hist, wsum, 2048, pre0, 10, w0, &s_prefix, &s_want);
            uint32_t pre1 = s_prefix, w1 = s_want;
            for (int i = tid; i < 1024; i += TK_BS) hist[i] = 0;
            __syncthreads();
            for (int i = tid; i < (int)T; i += TK_BS)
                if ((tk[i] >> 10) == (pre1 >> 10)) atomicAdd(&hist[tk[i] & 1023u], 1u);
            __syncthreads();
            suffix_select(hist, wsum, 1024, pre1, 0, w1, &s_prefix, &s_want);
            kth = s_prefix; rfin = s_want;
            for (int i = tid; i < (int)T; i += TK_BS) {
                uint32_t k = tk[i];
                if (k > kth) {
                    uint32_t p = atomicAdd(&ngt, 1u);
                    if (p < 256) { e_val[p] = fkey_inv(k); e_idx[p] = tix[i]; }
                } else if (k == kth) {
                    uint32_t p = atomicAdd(&ntie, 1u);
                    if (p < 256) tiebuf[p] = tix[i];
                }
            }
            __syncthreads();
        }
    } else {
        // ---- fallback: exact 2-sweep histogram path ----
        e_val[tid] = -1.0f; e_idx[tid] = tid;
        if (tid == 0) { ngt = 0; ntie = 0; tcnt = 0; }
        for (int i = tid; i < 2048; i += TK_BS) hist[i] = 0;
        __syncthreads();
        for (int i = tid; i < n4; i += TK_BS) {
            float4 f = v4[i];
            atomicAdd(&hist[fkey(f.x > CONF_T ? f.x : -1.0f) >> 21], 1u);
            atomicAdd(&hist[fkey(f.y > CONF_T ? f.y : -1.0f) >> 21], 1u);
            atomicAdd(&hist[fkey(f.z > CONF_T ? f.z : -1.0f) >> 21], 1u);
            atomicAdd(&hist[fkey(f.w > CONF_T ? f.w : -1.0f) >> 21], 1u);
        }
        for (int i = (n4 << 2) + tid; i < N; i += TK_BS)
            atomicAdd(&hist[fkey(v[i] > CONF_T ? v[i] : -1.0f) >> 21], 1u);
        __syncthreads();
        suffix_select(hist, wsum, 2048, 0u, 21, M_TOP, &s_prefix, &s_want);
        uint32_t b0 = s_prefix >> 21;
        uint32_t want1 = s_want;
        bool collect_ties = (b0 != BIN_N1);
        for (int i = tid; i < N; i += TK_BS) {
            float f = v[i];
            float mv = f > CONF_T ? f : -1.0f;
            uint32_t k = fkey(mv);
            uint32_t bin = k >> 21;
            if (bin > b0) {
                uint32_t p = atomicAdd(&ngt, 1u);
                if (p < 256) { e_val[p] = mv; e_idx[p] = i; }
            } else if (bin == b0 && collect_ties) {
                uint32_t p = atomicAdd(&tcnt, 1u);
                if (p < TCAP) { tk[p] = k; tix[p] = i; }
            }
        }
        __syncthreads();
        if (collect_ties && tcnt <= TCAP) {
            int Tl = (int)tcnt;
            for (int i = tid; i < 2048; i += TK_BS) hist[i] = 0;
            __syncthreads();
            for (int i = tid; i < Tl; i += TK_BS) atomicAdd(&hist[(tk[i] >> 10) & 2047u], 1u);
            __syncthreads();
            suffix_select(hist, wsum, 2048, b0 << 21, 10, want1, &s_prefix, &s_want);
            uint32_t pre2 = s_prefix; uint32_t want2 = s_want;
            uint32_t b1 = (pre2 >> 10) & 2047u;
            for (int i = tid; i < 1024; i += TK_BS) hist[i] = 0;
            __syncthreads();
            for (int i = tid; i < Tl; i += TK_BS)
                if (((tk[i] >> 10) & 2047u) == b1) atomicAdd(&hist[tk[i] & 1023u], 1u);
            __syncthreads();
            suffix_select(hist, wsum, 1024, pre2, 0, want2, &s_prefix, &s_want);
            kth = s_prefix; rfin = s_want;
            for (int i = tid; i < Tl; i += TK_BS) {
                uint32_t k = tk[i];
                if (k > kth) {
                    uint32_t p = atomicAdd(&ngt, 1u);
                    if (p < 256) { e_val[p] = fkey_inv(k); e_idx[p] = tix[i]; }
                } else if (k == kth) {
                    uint32_t p = atomicAdd(&ntie, 1u);
                    if (p < 256) tiebuf[p] = tix[i];
                }
            }
            __syncthreads();
        } else if (collect_ties) {
            const int shifts[2] = {10, 0};
            const int nbins_[2] = {2048, 1024};
            if (tid == 0) { s_prefix = b0 << 21; s_want = want1; }
            __syncthreads();
            for (int lev = 0; lev < 2; lev++) {
                int shift = shifts[lev];
                int nb = nbins_[lev];
                uint32_t bmask = (uint32_t)nb - 1u;
                uint32_t pref = s_prefix, wantv = s_want;
                uint32_t pmask = 0xFFFFFFFFu << (shift + ((nb == 2048) ? 11 : 10));
                for (int i = tid; i < nb; i += TK_BS) hist[i] = 0;
                __syncthreads();
                for (int i = tid; i < N; i += TK_BS) {
                    float f = v[i];
                    uint32_t k = fkey(f > CONF_T ? f : -1.0f);
                    if ((k & pmask) == (pref & pmask)) atomicAdd(&hist[(k >> shift) & bmask], 1u);
                }
                __syncthreads();
                suffix_select(hist, wsum, nb, pref, shift, wantv, &s_prefix, &s_want);
            }
            kth = s_prefix; rfin = s_want;
            for (int i = tid; i < N; i += TK_BS) {
                float f = v[i];
                float mv = f > CONF_T ? f : -1.0f;
                uint32_t k = fkey(mv);
                if ((k >> 21) == b0) {
                    if (k > kth) {
                        uint32_t p = atomicAdd(&ngt, 1u);
                        if (p < 256) { e_val[p] = mv; e_idx[p] = i; }
                    } else if (k == kth) {
                        uint32_t p = atomicAdd(&ntie, 1u);
                        if (p < 256) tiebuf[p] = i;
                    }
                }
            }
            __syncthreads();
        }
    }

    // ---- ties, rank order, inline box decode -> LDS + cand ----
    uint32_t gcount = min(ngt, (uint32_t)M_TOP);
    uint32_t nt = min(ntie, 256u);
    if (tid < (int)nt) {
        int mine = tiebuf[tid];
        uint32_t rk = 0;
        for (uint32_t j = 0; j < nt; j++) if (tiebuf[j] < mine) rk++;
        if (rk < rfin) {
            uint32_t slot = gcount + rk;
            if (slot < M_TOP) { e_val[slot] = fkey_inv(kth); e_idx[slot] = mine; }
        }
    }
    __syncthreads();
    if (tid < M_TOP) {
        float mv = e_val[tid]; int mi = e_idx[tid];
        uint32_t mk = fkey(mv);
        uint32_t rk = 0;
        for (int j = 0; j < M_TOP; j++) {
            uint32_t jk = fkey(e_val[j]); int ji = e_idx[j];
            if (jk > mk || (jk == mk && ji < mi)) rk++;
        }
        float4 l = ((const float4*)loc)[(size_t)b * N + mi];
        float4 d = ((const float4*)dbox)[mi];
        float4 bx = decode_box(l, d);
        ((float4*)cand)[(size_t)row * M_TOP + rk] = bx;   // for out_kernel gather
        s_sc[rk] = mv;
        s_x1[rk] = bx.x; s_y1[rk] = bx.y; s_x2[rk] = bx.z; s_y2[rk] = bx.w;
    }
    __syncthreads();

    // ---- fused greedy NMS + compaction on wave 0 (serial-wave form) ----
    if (tid < 64) {
        int lane = tid;
        float x1[4], y1[4], x2[4], y2[4], ar[4], sv[4];
        int act[4], kf[4];
        #pragma unroll
        for (int s = 0; s < 4; s++) {
            int j = s * 64 + lane;
            if (j < M_TOP) {
                x1[s] = s_x1[j]; y1[s] = s_y1[j]; x2[s] = s_x2[j]; y2[s] = s_y2[j];
                ar[s] = (x2[s] - x1[s]) * (y2[s] - y1[s]);
                sv[s] = s_sc[j];
            } else { x1[s]=0.f; y1[s]=0.f; x2[s]=0.f; y2[s]=0.f; ar[s]=0.f; sv[s]=-1.0f; }
            act[s] = (sv[s] > CONF_T) ? 1 : 0;
            kf[s] = 0;
        }
        #pragma unroll
        for (int si = 0; si < 4; si++) {
            int lim = M_TOP - si * 64; if (lim > 64) lim = 64;
            for (int li = 0; li < lim; li++) {
                int a = __shfl(act[si], li);
                if (a) {
                    if (lane == li) kf[si] = 1;
                    float bx1 = __shfl(x1[si], li);
                    float by1 = __shfl(y1[si], li);
                    float bx2 = __shfl(x2[si], li);
                    float by2 = __shfl(y2[si], li);
                    float bar = __shfl(ar[si], li);
                    #pragma unroll
                    for (int s = 0; s < 4; s++) {
                        float xx1 = fmaxf(bx1, x1[s]);
                        float yy1 = fmaxf(by1, y1[s]);
                        float xx2 = fminf(bx2, x2[s]);
                        float yy2 = fminf(by2, y2[s]);
                        float inter = fmaxf(xx2 - xx1, 0.f) * fmaxf(yy2 - yy1, 0.f);
                        float uni = (ar[s] - inter) + bar;
                        float iou = inter / uni;
                        if (!(iou <= NMS_T)) act[s] = 0;   // NaN suppresses
                    }
                }
            }
        }
        unsigned long long ball[4];
        int total = 0;
        #pragma unroll
        for (int s = 0; s < 4; s++) { ball[s] = __ballot(kf[s] != 0); total += (int)__popcll(ball[s]); }
        int base = 0;
        if (lane == 0 && total > 0) base = atomicAdd(&pcnt[b], total);
        base = __shfl(base, 0);
        unsigned long long lower = (lane == 0) ? 0ull : (~0ull >> (64 - lane));
        int off = base;
        #pragma unroll
        for (int s = 0; s < 4; s++) {
            if (kf[s]) {
                int pos = off + (int)__popcll(ball[s] & lower);
                cmpval[(size_t)b * M + pos] = sv[s];
                cmpidx[(size_t)b * M + pos] = c * M_TOP + s * 64 + lane;
            }
            off += (int)__popcll(ball[s]);
        }
    }
}

// ---------------- Kernel E: top-200 of positives -> compact (val,idx) list ----------
#define GT_BS 1024
__global__ __launch_bounds__(GT_BS) void gtop_kernel(
        const float* __restrict__ cmpval, const int* __restrict__ cmpidx,
        const int* __restrict__ pcnt, float* __restrict__ gl_val,
        int* __restrict__ gl_idx, int* __restrict__ gl_cnt, int M) {
    int b = blockIdx.x;
    int tid = threadIdx.x;
    int P = pcnt[b];
    const float* cv = cmpval + (size_t)b * M;
    const int*   ci = cmpidx + (size_t)b * M;
    if (P <= M_TOP) {
        for (int i = tid; i < P; i += GT_BS) {
            gl_val[b * M_TOP + i] = cv[i];
            gl_idx[b * M_TOP + i] = ci[i];
        }
        if (tid == 0) gl_cnt[b] = P;
        return;
    }
    __shared__ uint32_t hist[256];
    __shared__ uint32_t s_prefix, s_want;
    __shared__ int tiebuf[256];
    __shared__ uint32_t ntie, wcnt;
    __shared__ int cutoff;
    if (tid == 0) { s_prefix = 0; s_want = M_TOP; }
    for (int pass = 0; pass < 4; pass++) {
        if (tid < 256) hist[tid] = 0;
        __syncthreads();
        uint32_t prefix = s_prefix;
        int shift = 24 - 8 * pass;
        for (int i = tid; i < P; i += GT_BS) {
            uint32_t k = fkey(cv[i]);
            bool ok = (pass == 0) || ((k >> (shift + 8)) == (prefix >> (shift + 8)));
            if (ok) atomicAdd(&hist[(k >> shift) & 255u], 1u);
        }
        __syncthreads();
        if (tid == 0) {
            uint32_t want = s_want, cum = 0; int bin = 0;
            for (int bb = 255; bb >= 0; bb--) {
                if (cum + hist[bb] >= want) { bin = bb; break; }
                cum += hist[bb];
            }
            s_want = want - cum;
            s_prefix = prefix | ((uint32_t)bin << shift);
        }
        __syncthreads();
    }
    uint32_t kth = s_prefix, rfin = s_want;
    if (tid == 0) { ntie = 0; cutoff = -1; wcnt = 0; }
    __syncthreads();
    for (int i = tid; i < P; i += GT_BS) {
        if (fkey(cv[i]) == kth) { uint32_t p = atomicAdd(&ntie, 1u); if (p < 256) tiebuf[p] = ci[i]; }
    }
    __syncthreads();
    uint32_t nt = min(ntie, 256u);
    if (tid < (int)nt) {
        int mine = tiebuf[tid];
        uint32_t rk = 0;
        for (uint32_t j = 0; j < nt; j++) if (tiebuf[j] < mine) rk++;
        if (rk == rfin - 1) cutoff = mine;
    }
    __syncthreads();
    int cut = cutoff;
    for (int i = tid; i < P; i += GT_BS) {
        uint32_t k = fkey(cv[i]);
        if (k > kth || (k == kth && ci[i] <= cut)) {
            uint32_t p = atomicAdd(&wcnt, 1u);
            gl_val[b * M_TOP + p] = cv[i];
            gl_idx[b * M_TOP + p] = ci[i];
        }
    }
    if (tid == 0) gl_cnt[b] = M_TOP;
}

// ---------------- Kernel F: per-class sort + FULL output write (no memset) ----------
__global__ __launch_bounds__(256) void out_kernel(
        const float* __restrict__ gl_val, const int* __restrict__ gl_idx,
        const int* __restrict__ gl_cnt, const float* __restrict__ cand,
        float* __restrict__ out, int C, int Cm1) {
    int row = blockIdx.x;   // b*C + cc
    int b = row / C, cc = row % C;
    int tid = threadIdx.x;
    size_t oslab = (size_t)row * M_TOP * 5;
    if (cc == 0) {                         // background class: zero-fill (float4)
        float4 z; z.x = 0.f; z.y = 0.f; z.z = 0.f; z.w = 0.f;
        float4* o4 = (float4*)(out + oslab);
        for (int i = tid; i < M_TOP * 5 / 4; i += 256) o4[i] = z;
        return;
    }
    int c = cc - 1;
    __shared__ float lv[M_TOP];
    __shared__ int   lm[M_TOP];
    __shared__ uint32_t nloc;
    if (tid == 0) nloc = 0;
    __syncthreads();
    int cnt = gl_cnt[b];
    for (int i = tid; i < cnt; i += 256) {
        int idx = gl_idx[b * M_TOP + i];
        if (idx / M_TOP == c) {
            uint32_t p = atomicAdd(&nloc, 1u);
            lv[p] = gl_val[b * M_TOP + i];
            lm[p] = idx % M_TOP;
        }
    }
    __syncthreads();
    int nc = (int)nloc;
    if (tid < M_TOP) {
        if (tid < nc) {
            float v = lv[tid]; int m = lm[tid];
            int rk = 0;
            for (int j = 0; j < nc; j++)
                if (lv[j] > v || (lv[j] == v && lm[j] < m)) rk++;
            float4 bb = ((const float4*)cand)[((size_t)(b * Cm1 + c)) * M_TOP + m];
            size_t o = oslab + (size_t)rk * 5;
            out[o] = v; out[o + 1] = bb.x; out[o + 2] = bb.y;
            out[o + 3] = bb.z; out[o + 4] = bb.w;
        } else {
            size_t o = oslab + (size_t)tid * 5;
            out[o] = 0.f; out[o + 1] = 0.f; out[o + 2] = 0.f;
            out[o + 3] = 0.f; out[o + 4] = 0.f;
        }
    }
}

extern "C" void kernel_launch(void* const* d_in, const int* in_sizes, int n_in,
                              void* d_out, int out_size, void* d_ws, size_t ws_size,
                              hipStream_t stream) {
    const float* loc  = (const float*)d_in[0];
    const float* conf = (const float*)d_in[1];
    const float* dbox = (const float*)d_in[2];
    int N   = in_sizes[2] / 4;
    int B   = in_sizes[0] / (4 * N);
    int C   = in_sizes[1] / (B * N);
    int Cm1 = C - 1;
    int M   = Cm1 * M_TOP;                 // 16000 per batch

    char* ws = (char*)d_ws;
    size_t off = 0;
    auto alloc = [&](size_t bytes) -> char* {
        char* p = ws + off;
        off = (off + bytes + 255) & ~(size_t)255;
        return p;
    };
    float* sc     = (float*)alloc((size_t)B * Cm1 * N * sizeof(float));
    float* cand   = (float*)alloc((size_t)B * M * 4 * sizeof(float));
    int*   pcnt   = (int*)alloc((size_t)B * sizeof(int));
    float* cmpval = (float*)alloc((size_t)B * M * sizeof(float));
    int*   cmpidx = (int*)alloc((size_t)B * M * sizeof(int));
    float* gl_val = (float*)alloc((size_t)B * M_TOP * sizeof(float));
    int*   gl_idx = (int*)alloc((size_t)B * M_TOP * sizeof(int));
    int*   gl_cnt = (int*)alloc((size_t)B * sizeof(int));

    int bn = B * N;
    softmax_kernel<<<(bn + 255) / 256, 256, 0, stream>>>(conf, sc, pcnt, B, N, C);
    topk_kernel<<<B * Cm1, TK_BS, 0, stream>>>(sc, loc, dbox, cand, cmpval, cmpidx, pcnt,
                                               B, N, Cm1, M);
    gtop_kernel<<<B, GT_BS, 0, stream>>>(cmpval, cmpidx, pcnt, gl_val, gl_idx, gl_cnt, M);
    out_kernel<<<B * C, 256, 0, stream>>>(gl_val, gl_idx, gl_cnt, cand, (float*)d_out, C, Cm1);
}

// Round 17
// 269.629 us; speedup vs baseline: 1.0640x; 1.0329x over previous
//
#include <hip/hip_runtime.h>
#include <stdint.h>

#define CONF_T 0.01f
#define NMS_T  0.45f
#define M_TOP  200
#define TK_BS  512    // topk block size (8 waves; grid-limited -> 2x resident waves/CU)
#define TCAP   2048   // topk bracket buffer capacity (LDS); overflow -> exact fallback

typedef float float4u __attribute__((ext_vector_type(4), aligned(4)));

__device__ __forceinline__ uint32_t fkey(float f) {
    uint32_t u = __float_as_uint(f);
    return (u & 0x80000000u) ? ~u : (u | 0x80000000u);
}
__device__ __forceinline__ float fkey_inv(uint32_t k) {
    uint32_t u = (k & 0x80000000u) ? (k & 0x7FFFFFFFu) : ~k;
    return __uint_as_float(u);
}

// Parallel suffix-scan bin selection over nb bins (nb multiple of 256).
// Scan work is done by threads 0..255; all TK_BS threads must reach barriers.
__device__ __forceinline__ void suffix_select(
        uint32_t* hist, uint32_t* wsum, int nb, uint32_t pref, int shift,
        uint32_t wantv, uint32_t* s_prefix, uint32_t* s_want) {
    int tid = threadIdx.x;
    int lane = tid & 63, w = tid >> 6;
    int bpt = nb >> 8;
    int base = tid * bpt;
    uint32_t loc = 0, sfx = 0;
    if (tid < 256) {
        for (int j = 0; j < bpt; j++) loc += hist[base + j];
        sfx = loc;
        #pragma unroll
        for (int d = 1; d < 64; d <<= 1) {
            uint32_t y = __shfl_down(sfx, d);
            if (lane + d < 64) sfx += y;
        }
        if (lane == 0) wsum[w] = sfx;
    }
    __syncthreads();
    if (tid < 256) {
        uint32_t later = 0;
        for (int j = w + 1; j < 4; j++) later += wsum[j];
        uint32_t run = (sfx - loc) + later;
        for (int j = bpt - 1; j >= 0; j--) {
            uint32_t h = hist[base + j];
            uint32_t s2 = run + h;
            if (run < wantv && s2 >= wantv) {
                *s_prefix = pref | ((uint32_t)(base + j) << shift);
                *s_want   = wantv - run;
            }
            run = s2;
        }
    }
    __syncthreads();
}

// Dual-rank variant: boundary bins for TWO wants in one scan.
__device__ __forceinline__ void suffix_select2(
        uint32_t* hist, uint32_t* wsum, int nb, uint32_t want_a, uint32_t want_b,
        uint32_t* s_bin_a, uint32_t* s_bin_b) {
    int tid = threadIdx.x;
    int lane = tid & 63, w = tid >> 6;
    int bpt = nb >> 8;
    int base = tid * bpt;
    uint32_t loc = 0, sfx = 0;
    if (tid < 256) {
        for (int j = 0; j < bpt; j++) loc += hist[base + j];
        sfx = loc;
        #pragma unroll
        for (int d = 1; d < 64; d <<= 1) {
            uint32_t y = __shfl_down(sfx, d);
            if (lane + d < 64) sfx += y;
        }
        if (lane == 0) wsum[w] = sfx;
    }
    __syncthreads();
    if (tid < 256) {
        uint32_t later = 0;
        for (int j = w + 1; j < 4; j++) later += wsum[j];
        uint32_t run = (sfx - loc) + later;
        for (int j = bpt - 1; j >= 0; j--) {
            uint32_t h = hist[base + j];
            uint32_t s2 = run + h;
            if (run < want_a && s2 >= want_a) *s_bin_a = (uint32_t)(base + j);
            if (run < want_b && s2 >= want_b) *s_bin_b = (uint32_t)(base + j);
            run = s2;
        }
    }
    __syncthreads();
}

__device__ __forceinline__ float4 decode_box(float4 l, float4 d) {
    float cx = d.x + (l.x * 0.1f) * d.z;
    float cy = d.y + (l.y * 0.1f) * d.w;
    float w  = d.z * expf(l.z * 0.2f);
    float h  = d.w * expf(l.w * 0.2f);
    float x1 = cx - w * 0.5f, y1 = cy - h * 0.5f;
    float x2 = x1 + w, y2 = y1 + h;
    float4 o;
    o.x = fminf(fmaxf(x1, 0.f), 1.f);
    o.y = fminf(fmaxf(y1, 0.f), 1.f);
    o.z = fminf(fmaxf(x2, 0.f), 1.f);
    o.w = fminf(fmaxf(y2, 0.f), 1.f);
    return o;
}

// ---------------- Kernel B: softmax + transpose (register-resident) + pcnt init ------
__global__ __launch_bounds__(256, 4) void softmax_kernel(
        const float* __restrict__ conf, float* __restrict__ sc,
        int* __restrict__ pcnt, int B, int N, int C) {
    int r = blockIdx.x * blockDim.x + threadIdx.x;
    if (r < B) pcnt[r] = 0;                 // zero pcnt for the topk dispatch
    if (r >= B * N) return;
    const float* p = conf + (size_t)r * 81;
    float v[81];
    #pragma unroll
    for (int i = 0; i < 20; i++) {
        float4u f = *(const float4u*)(p + 4 * i);
        v[4 * i] = f.x; v[4 * i + 1] = f.y; v[4 * i + 2] = f.z; v[4 * i + 3] = f.w;
    }
    v[80] = p[80];
    float m = v[0];
    #pragma unroll
    for (int c = 1; c < 81; c++) m = fmaxf(m, v[c]);
    float s = 0.f;
    #pragma unroll
    for (int c = 0; c < 81; c++) { float e = expf(v[c] - m); v[c] = e; s += e; }
    int b = r / N, n = r % N;
    float* obase = sc + ((size_t)b * (C - 1)) * N + n;
    #pragma unroll
    for (int c = 1; c < 81; c++) obase[(size_t)(c - 1) * N] = v[c] / s;
}

// ---------------- Kernel C: top-200 + inline decode + fused serial-wave NMS ----------
__global__ __launch_bounds__(TK_BS) void topk_kernel(
        const float* __restrict__ sc, const float* __restrict__ loc,
        const float* __restrict__ dbox,
        float* __restrict__ cand,
        float* __restrict__ cmpval, int* __restrict__ cmpidx,
        int* __restrict__ pcnt,
        int B, int N, int Cm1, int M) {
    const uint32_t KEYN1 = 0x407FFFFFu;        // fkey(-1.0f)
    const uint32_t BIN_N1 = KEYN1 >> 21;       // 0x203
    __shared__ __align__(16) uint32_t hist[2048];
    __shared__ __align__(16) uint32_t tk[TCAP];
    __shared__ int      tix[TCAP];
    __shared__ uint32_t wsum[4];
    __shared__ uint32_t s_prefix, s_want, s_bin_a, s_bin_b;
    __shared__ uint32_t ngt, ntie, tcnt;
    __shared__ float    e_val[256];
    __shared__ int      e_idx[256];
    __shared__ int      tiebuf[256];
    __shared__ float    s_sc[M_TOP];
    __shared__ float    s_x1[M_TOP], s_y1[M_TOP], s_x2[M_TOP], s_y2[M_TOP];

    int row = blockIdx.x;                      // b*Cm1 + c
    int b = row / Cm1, c = row % Cm1;
    int tid = threadIdx.x;
    const float* v = sc + (size_t)row * N;
    const float4* v4 = (const float4*)v;
    int n4 = N >> 2;

    // ---- sample phase: 2048 strided samples (4 segments x 512 threads) ----
    bool sampled = (N >= 2048) && ((N & 3) == 0);
    uint32_t lo_key = 0xFFFFFFFFu, hi_key = 0xFFFFFFFFu;
    if (sampled) {
        int stride = N >> 2;
        for (int s = 0; s < 4; s++) {
            float f = v[s * stride + tid];
            tk[s * 512 + tid] = fkey(f > CONF_T ? f : -1.0f);
        }
        for (int i = tid; i < 2048; i += TK_BS) hist[i] = 0;
        __syncthreads();
        for (int i = tid; i < 2048; i += TK_BS) atomicAdd(&hist[tk[i] >> 21], 1u);
        __syncthreads();
        suffix_select2(hist, wsum, 2048, 3u, 25u, &s_bin_a, &s_bin_b);
        uint32_t h = s_bin_a, l = s_bin_b;
        hi_key = ((h + 1) << 21) - 1u;         // h=2047 wraps to 0xFFFFFFFF (G=0)
        lo_key = (l << 21) - 1u;
        sampled = (l > BIN_N1);
    }

    if (tid < 256) { e_val[tid] = -1.0f; e_idx[tid] = tid; }
    if (tid == 0) { ngt = 0; ntie = 0; tcnt = 0; }
    __syncthreads();

    bool ok = false;
    uint32_t G = 0, T = 0;
    if (sampled) {
        // ---- the one full sweep: 8-way unrolled batch loads for MLP ----
        for (int i0 = tid; i0 < n4; i0 += 8 * TK_BS) {
            float4 f[8];
            #pragma unroll
            for (int u = 0; u < 8; u++) {
                int i = i0 + u * TK_BS;
                if (i < n4) f[u] = v4[i];
            }
            #pragma unroll
            for (int u = 0; u < 8; u++) {
                int i = i0 + u * TK_BS;
                if (i < n4) {
                    float mv[4] = { f[u].x > CONF_T ? f[u].x : -1.0f,
                                    f[u].y > CONF_T ? f[u].y : -1.0f,
                                    f[u].z > CONF_T ? f[u].z : -1.0f,
                                    f[u].w > CONF_T ? f[u].w : -1.0f };
                    #pragma unroll
                    for (int j = 0; j < 4; j++) {
                        uint32_t k = fkey(mv[j]);
                        if (k > lo_key) {
                            int idx = 4 * i + j;
                            if (k > hi_key) {
                                uint32_t p = atomicAdd(&ngt, 1u);
                                if (p < 256) { e_val[p] = mv[j]; e_idx[p] = idx; }
                            } else {
                                uint32_t p = atomicAdd(&tcnt, 1u);
                                if (p < TCAP) { tk[p] = k; tix[p] = idx; }
                            }
                        }
                    }
                }
            }
        }
        for (int i = (n4 << 2) + tid; i < N; i += TK_BS) {
            float f = v[i];
            float mv = f > CONF_T ? f : -1.0f;
            uint32_t k = fkey(mv);
            if (k > lo_key) {
                if (k > hi_key) {
                    uint32_t p = atomicAdd(&ngt, 1u);
                    if (p < 256) { e_val[p] = mv; e_idx[p] = i; }
                } else {
                    uint32_t p = atomicAdd(&tcnt, 1u);
                    if (p < TCAP) { tk[p] = k; tix[p] = i; }
                }
            }
        }
        __syncthreads();
        G = ngt; T = tcnt;
        ok = (G <= (uint32_t)M_TOP) && (T <= (uint32_t)TCAP) &&
             (G + T >= (uint32_t)M_TOP);
    }

    uint32_t kth = KEYN1, rfin = 0;
    if (ok) {
        uint32_t want_t = (uint32_t)M_TOP - G;
        if (want_t > 0) {
            for (int i = tid; i < 2048; i += TK_BS) hist[i] = 0;
            __syncthreads();
            for (int i = tid; i < (int)T; i += TK_BS) atomicAdd(&hist[tk[i] >> 21], 1u);
            __syncthreads();
            suffix_select(hist, wsum, 2048, 0u, 21, want_t, &s_prefix, &s_want);
            uint32_t pre0 = s_prefix, w0 = s_want;
            uint32_t bb0 = pre0 >> 21;
            for (int i = tid; i < 2048; i += TK_BS) hist[i] = 0;
            __syncthreads();
            for (int i = tid; i < (int)T; i += TK_BS)
                if ((tk[i] >> 21) == bb0) atomicAdd(&hist[(tk[i] >> 10) & 2047u], 1u);
            __syncthreads();
            suffix_select(hist, wsum, 2048, pre0, 10, w0, &s_prefix, &s_want);
            uint32_t pre1 = s_prefix, w1 = s_want;
            for (int i = tid; i < 1024; i += TK_BS) hist[i] = 0;
            __syncthreads();
            for (int i = tid; i < (int)T; i += TK_BS)
                if ((tk[i] >> 10) == (pre1 >> 10)) atomicAdd(&hist[tk[i] & 1023u], 1u);
            __syncthreads();
            suffix_select(hist, wsum, 1024, pre1, 0, w1, &s_prefix, &s_want);
            kth = s_prefix; rfin = s_want;
            for (int i = tid; i < (int)T; i += TK_BS) {
                uint32_t k = tk[i];
                if (k > kth) {
                    uint32_t p = atomicAdd(&ngt, 1u);
                    if (p < 256) { e_val[p] = fkey_inv(k); e_idx[p] = tix[i]; }
                } else if (k == kth) {
                    uint32_t p = atomicAdd(&ntie, 1u);
                    if (p < 256) tiebuf[p] = tix[i];
                }
            }
            __syncthreads();
        }
    } else {
        // ---- fallback: exact 2-sweep histogram path ----
        if (tid < 256) { e_val[tid] = -1.0f; e_idx[tid] = tid; }
        if (tid == 0) { ngt = 0; ntie = 0; tcnt = 0; }
        for (int i = tid; i < 2048; i += TK_BS) hist[i] = 0;
        __syncthreads();
        for (int i = tid; i < n4; i += TK_BS) {
            float4 f = v4[i];
            atomicAdd(&hist[fkey(f.x > CONF_T ? f.x : -1.0f) >> 21], 1u);
            atomicAdd(&hist[fkey(f.y > CONF_T ? f.y : -1.0f) >> 21], 1u);
            atomicAdd(&hist[fkey(f.z > CONF_T ? f.z : -1.0f) >> 21], 1u);
            atomicAdd(&hist[fkey(f.w > CONF_T ? f.w : -1.0f) >> 21], 1u);
        }
        for (int i = (n4 << 2) + tid; i < N; i += TK_BS)
            atomicAdd(&hist[fkey(v[i] > CONF_T ? v[i] : -1.0f) >> 21], 1u);
        __syncthreads();
        suffix_select(hist, wsum, 2048, 0u, 21, M_TOP, &s_prefix, &s_want);
        uint32_t b0 = s_prefix >> 21;
        uint32_t want1 = s_want;
        bool collect_ties = (b0 != BIN_N1);
        for (int i = tid; i < N; i += TK_BS) {
            float f = v[i];
            float mv = f > CONF_T ? f : -1.0f;
            uint32_t k = fkey(mv);
            uint32_t bin = k >> 21;
            if (bin > b0) {
                uint32_t p = atomicAdd(&ngt, 1u);
                if (p < 256) { e_val[p] = mv; e_idx[p] = i; }
            } else if (bin == b0 && collect_ties) {
                uint32_t p = atomicAdd(&tcnt, 1u);
                if (p < TCAP) { tk[p] = k; tix[p] = i; }
            }
        }
        __syncthreads();
        if (collect_ties && tcnt <= TCAP) {
            int Tl = (int)tcnt;
            for (int i = tid; i < 2048; i += TK_BS) hist[i] = 0;
            __syncthreads();
            for (int i = tid; i < Tl; i += TK_BS) atomicAdd(&hist[(tk[i] >> 10) & 2047u], 1u);
            __syncthreads();
            suffix_select(hist, wsum, 2048, b0 << 21, 10, want1, &s_prefix, &s_want);
            uint32_t pre2 = s_prefix; uint32_t want2 = s_want;
            uint32_t b1 = (pre2 >> 10) & 2047u;
            for (int i = tid; i < 1024; i += TK_BS) hist[i] = 0;
            __syncthreads();
            for (int i = tid; i < Tl; i += TK_BS)
                if (((tk[i] >> 10) & 2047u) == b1) atomicAdd(&hist[tk[i] & 1023u], 1u);
            __syncthreads();
            suffix_select(hist, wsum, 1024, pre2, 0, want2, &s_prefix, &s_want);
            kth = s_prefix; rfin = s_want;
            for (int i = tid; i < Tl; i += TK_BS) {
                uint32_t k = tk[i];
                if (k > kth) {
                    uint32_t p = atomicAdd(&ngt, 1u);
                    if (p < 256) { e_val[p] = fkey_inv(k); e_idx[p] = tix[i]; }
                } else if (k == kth) {
                    uint32_t p = atomicAdd(&ntie, 1u);
                    if (p < 256) tiebuf[p] = tix[i];
                }
            }
            __syncthreads();
        } else if (collect_ties) {
            const int shifts[2] = {10, 0};
            const int nbins_[2] = {2048, 1024};
            if (tid == 0) { s_prefix = b0 << 21; s_want = want1; }
            __syncthreads();
            for (int lev = 0; lev < 2; lev++) {
                int shift = shifts[lev];
                int nb = nbins_[lev];
                uint32_t bmask = (uint32_t)nb - 1u;
                uint32_t pref = s_prefix, wantv = s_want;
                uint32_t pmask = 0xFFFFFFFFu << (shift + ((nb == 2048) ? 11 : 10));
                for (int i = tid; i < nb; i += TK_BS) hist[i] = 0;
                __syncthreads();
                for (int i = tid; i < N; i += TK_BS) {
                    float f = v[i];
                    uint32_t k = fkey(f > CONF_T ? f : -1.0f);
                    if ((k & pmask) == (pref & pmask)) atomicAdd(&hist[(k >> shift) & bmask], 1u);
                }
                __syncthreads();
                suffix_select(hist, wsum, nb, pref, shift, wantv, &s_prefix, &s_want);
            }
            kth = s_prefix; rfin = s_want;
            for (int i = tid; i < N; i += TK_BS) {
                float f = v[i];
                float mv = f > CONF_T ? f : -1.0f;
                uint32_t k = fkey(mv);
                if ((k >> 21) == b0) {
                    if (k > kth) {
                        uint32_t p = atomicAdd(&ngt, 1u);
                        if (p < 256) { e_val[p] = mv; e_idx[p] = i; }
                    } else if (k == kth) {
                        uint32_t p = atomicAdd(&ntie, 1u);
                        if (p < 256) tiebuf[p] = i;
                    }
                }
            }
            __syncthreads();
        }
    }

    // ---- ties, rank order, inline box decode -> LDS + cand ----
    uint32_t gcount = min(ngt, (uint32_t)M_TOP);
    uint32_t nt = min(ntie, 256u);
    if (tid < (int)nt) {
        int mine = tiebuf[tid];
        uint32_t rk = 0;
        for (uint32_t j = 0; j < nt; j++) if (tiebuf[j] < mine) rk++;
        if (rk < rfin) {
            uint32_t slot = gcount + rk;
            if (slot < M_TOP) { e_val[slot] = fkey_inv(kth); e_idx[slot] = mine; }
        }
    }
    __syncthreads();
    if (tid < M_TOP) {
        float mv = e_val[tid]; int mi = e_idx[tid];
        uint32_t mk = fkey(mv);
        uint32_t rk = 0;
        for (int j = 0; j < M_TOP; j++) {
            uint32_t jk = fkey(e_val[j]); int ji = e_idx[j];
            if (jk > mk || (jk == mk && ji < mi)) rk++;
        }
        float4 l = ((const float4*)loc)[(size_t)b * N + mi];
        float4 d = ((const float4*)dbox)[mi];
        float4 bx = decode_box(l, d);
        ((float4*)cand)[(size_t)row * M_TOP + rk] = bx;   // for out_kernel gather
        s_sc[rk] = mv;
        s_x1[rk] = bx.x; s_y1[rk] = bx.y; s_x2[rk] = bx.z; s_y2[rk] = bx.w;
    }
    __syncthreads();

    // ---- fused greedy NMS + compaction on wave 0 (serial-wave form) ----
    if (tid < 64) {
        int lane = tid;
        float x1[4], y1[4], x2[4], y2[4], ar[4], sv[4];
        int act[4], kf[4];
        #pragma unroll
        for (int s = 0; s < 4; s++) {
            int j = s * 64 + lane;
            if (j < M_TOP) {
                x1[s] = s_x1[j]; y1[s] = s_y1[j]; x2[s] = s_x2[j]; y2[s] = s_y2[j];
                ar[s] = (x2[s] - x1[s]) * (y2[s] - y1[s]);
                sv[s] = s_sc[j];
            } else { x1[s]=0.f; y1[s]=0.f; x2[s]=0.f; y2[s]=0.f; ar[s]=0.f; sv[s]=-1.0f; }
            act[s] = (sv[s] > CONF_T) ? 1 : 0;
            kf[s] = 0;
        }
        #pragma unroll
        for (int si = 0; si < 4; si++) {
            int lim = M_TOP - si * 64; if (lim > 64) lim = 64;
            for (int li = 0; li < lim; li++) {
                int a = __shfl(act[si], li);
                if (a) {
                    if (lane == li) kf[si] = 1;
                    float bx1 = __shfl(x1[si], li);
                    float by1 = __shfl(y1[si], li);
                    float bx2 = __shfl(x2[si], li);
                    float by2 = __shfl(y2[si], li);
                    float bar = __shfl(ar[si], li);
                    #pragma unroll
                    for (int s = 0; s < 4; s++) {
                        float xx1 = fmaxf(bx1, x1[s]);
                        float yy1 = fmaxf(by1, y1[s]);
                        float xx2 = fminf(bx2, x2[s]);
                        float yy2 = fminf(by2, y2[s]);
                        float inter = fmaxf(xx2 - xx1, 0.f) * fmaxf(yy2 - yy1, 0.f);
                        float uni = (ar[s] - inter) + bar;
                        float iou = inter / uni;
                        if (!(iou <= NMS_T)) act[s] = 0;   // NaN suppresses
                    }
                }
            }
        }
        unsigned long long ball[4];
        int total = 0;
        #pragma unroll
        for (int s = 0; s < 4; s++) { ball[s] = __ballot(kf[s] != 0); total += (int)__popcll(ball[s]); }
        int base = 0;
        if (lane == 0 && total > 0) base = atomicAdd(&pcnt[b], total);
        base = __shfl(base, 0);
        unsigned long long lower = (lane == 0) ? 0ull : (~0ull >> (64 - lane));
        int off = base;
        #pragma unroll
        for (int s = 0; s < 4; s++) {
            if (kf[s]) {
                int pos = off + (int)__popcll(ball[s] & lower);
                cmpval[(size_t)b * M + pos] = sv[s];
                cmpidx[(size_t)b * M + pos] = c * M_TOP + s * 64 + lane;
            }
            off += (int)__popcll(ball[s]);
        }
    }
}

// ---------------- Kernel E: top-200 of positives -> compact (val,idx) list ----------
#define GT_BS 1024
__global__ __launch_bounds__(GT_BS) void gtop_kernel(
        const float* __restrict__ cmpval, const int* __restrict__ cmpidx,
        const int* __restrict__ pcnt, float* __restrict__ gl_val,
        int* __restrict__ gl_idx, int* __restrict__ gl_cnt, int M) {
    int b = blockIdx.x;
    int tid = threadIdx.x;
    int P = pcnt[b];
    const float* cv = cmpval + (size_t)b * M;
    const int*   ci = cmpidx + (size_t)b * M;
    if (P <= M_TOP) {
        for (int i = tid; i < P; i += GT_BS) {
            gl_val[b * M_TOP + i] = cv[i];
            gl_idx[b * M_TOP + i] = ci[i];
        }
        if (tid == 0) gl_cnt[b] = P;
        return;
    }
    __shared__ uint32_t hist[256];
    __shared__ uint32_t s_prefix, s_want;
    __shared__ int tiebuf[256];
    __shared__ uint32_t ntie, wcnt;
    __shared__ int cutoff;
    if (tid == 0) { s_prefix = 0; s_want = M_TOP; }
    for (int pass = 0; pass < 4; pass++) {
        if (tid < 256) hist[tid] = 0;
        __syncthreads();
        uint32_t prefix = s_prefix;
        int shift = 24 - 8 * pass;
        for (int i = tid; i < P; i += GT_BS) {
            uint32_t k = fkey(cv[i]);
            bool ok = (pass == 0) || ((k >> (shift + 8)) == (prefix >> (shift + 8)));
            if (ok) atomicAdd(&hist[(k >> shift) & 255u], 1u);
        }
        __syncthreads();
        if (tid == 0) {
            uint32_t want = s_want, cum = 0; int bin = 0;
            for (int bb = 255; bb >= 0; bb--) {
                if (cum + hist[bb] >= want) { bin = bb; break; }
                cum += hist[bb];
            }
            s_want = want - cum;
            s_prefix = prefix | ((uint32_t)bin << shift);
        }
        __syncthreads();
    }
    uint32_t kth = s_prefix, rfin = s_want;
    if (tid == 0) { ntie = 0; cutoff = -1; wcnt = 0; }
    __syncthreads();
    for (int i = tid; i < P; i += GT_BS) {
        if (fkey(cv[i]) == kth) { uint32_t p = atomicAdd(&ntie, 1u); if (p < 256) tiebuf[p] = ci[i]; }
    }
    __syncthreads();
    uint32_t nt = min(ntie, 256u);
    if (tid < (int)nt) {
        int mine = tiebuf[tid];
        uint32_t rk = 0;
        for (uint32_t j = 0; j < nt; j++) if (tiebuf[j] < mine) rk++;
        if (rk == rfin - 1) cutoff = mine;
    }
    __syncthreads();
    int cut = cutoff;
    for (int i = tid; i < P; i += GT_BS) {
        uint32_t k = fkey(cv[i]);
        if (k > kth || (k == kth && ci[i] <= cut)) {
            uint32_t p = atomicAdd(&wcnt, 1u);
            gl_val[b * M_TOP + p] = cv[i];
            gl_idx[b * M_TOP + p] = ci[i];
        }
    }
    if (tid == 0) gl_cnt[b] = M_TOP;
}

// ---------------- Kernel F: per-class sort + FULL output write (no memset) ----------
__global__ __launch_bounds__(256) void out_kernel(
        const float* __restrict__ gl_val, const int* __restrict__ gl_idx,
        const int* __restrict__ gl_cnt, const float* __restrict__ cand,
        float* __restrict__ out, int C, int Cm1) {
    int row = blockIdx.x;   // b*C + cc
    int b = row / C, cc = row % C;
    int tid = threadIdx.x;
    size_t oslab = (size_t)row * M_TOP * 5;
    if (cc == 0) {                         // background class: zero-fill (float4)
        float4 z; z.x = 0.f; z.y = 0.f; z.z = 0.f; z.w = 0.f;
        float4* o4 = (float4*)(out + oslab);
        for (int i = tid; i < M_TOP * 5 / 4; i += 256) o4[i] = z;
        return;
    }
    int c = cc - 1;
    __shared__ float lv[M_TOP];
    __shared__ int   lm[M_TOP];
    __shared__ uint32_t nloc;
    if (tid == 0) nloc = 0;
    __syncthreads();
    int cnt = gl_cnt[b];
    for (int i = tid; i < cnt; i += 256) {
        int idx = gl_idx[b * M_TOP + i];
        if (idx / M_TOP == c) {
            uint32_t p = atomicAdd(&nloc, 1u);
            lv[p] = gl_val[b * M_TOP + i];
            lm[p] = idx % M_TOP;
        }
    }
    __syncthreads();
    int nc = (int)nloc;
    if (tid < M_TOP) {
        if (tid < nc) {
            float v = lv[tid]; int m = lm[tid];
            int rk = 0;
            for (int j = 0; j < nc; j++)
                if (lv[j] > v || (lv[j] == v && lm[j] < m)) rk++;
            float4 bb = ((const float4*)cand)[((size_t)(b * Cm1 + c)) * M_TOP + m];
            size_t o = oslab + (size_t)rk * 5;
            out[o] = v; out[o + 1] = bb.x; out[o + 2] = bb.y;
            out[o + 3] = bb.z; out[o + 4] = bb.w;
        } else {
            size_t o = oslab + (size_t)tid * 5;
            out[o] = 0.f; out[o + 1] = 0.f; out[o + 2] = 0.f;
            out[o + 3] = 0.f; out[o + 4] = 0.f;
        }
    }
}

extern "C" void kernel_launch(void* const* d_in, const int* in_sizes, int n_in,
                              void* d_out, int out_size, void* d_ws, size_t ws_size,
                              hipStream_t stream) {
    const float* loc  = (const float*)d_in[0];
    const float* conf = (const float*)d_in[1];
    const float* dbox = (const float*)d_in[2];
    int N   = in_sizes[2] / 4;
    int B   = in_sizes[0] / (4 * N);
    int C   = in_sizes[1] / (B * N);
    int Cm1 = C - 1;
    int M   = Cm1 * M_TOP;                 // 16000 per batch

    char* ws = (char*)d_ws;
    size_t off = 0;
    auto alloc = [&](size_t bytes) -> char* {
        char* p = ws + off;
        off = (off + bytes + 255) & ~(size_t)255;
        return p;
    };
    float* sc     = (float*)alloc((size_t)B * Cm1 * N * sizeof(float));
    float* cand   = (float*)alloc((size_t)B * M * 4 * sizeof(float));
    int*   pcnt   = (int*)alloc((size_t)B * sizeof(int));
    float* cmpval = (float*)alloc((size_t)B * M * sizeof(float));
    int*   cmpidx = (int*)alloc((size_t)B * M * sizeof(int));
    float* gl_val = (float*)alloc((size_t)B * M_TOP * sizeof(float));
    int*   gl_idx = (int*)alloc((size_t)B * M_TOP * sizeof(int));
    int*   gl_cnt = (int*)alloc((size_t)B * sizeof(int));

    int bn = B * N;
    softmax_kernel<<<(bn + 255) / 256, 256, 0, stream>>>(conf, sc, pcnt, B, N, C);
    topk_kernel<<<B * Cm1, TK_BS, 0, stream>>>(sc, loc, dbox, cand, cmpval, cmpidx, pcnt,
                                               B, N, Cm1, M);
    gtop_kernel<<<B, GT_BS, 0, stream>>>(cmpval, cmpidx, pcnt, gl_val, gl_idx, gl_cnt, M);
    out_kernel<<<B * C, 256, 0, stream>>>(gl_val, gl_idx, gl_cnt, cand, (float*)d_out, C, Cm1);
}